// Round 14
// baseline (117.963 us; speedup 1.0000x reference)
//
#include <hip/hip_runtime.h>

// Problem constants
#define M_ROWS 8192            // B*L = 4*2048
#define N_DIM  1024            // D
#define K3     3072            // 3*D
#define KD     16              // K_DIM
#define NKT    48              // K3 / BK (multiple of 3)
#define BM     256
#define BN     128
#define BK     64
#define LDS_A  (BM * BK)       // 16384 ushorts = 32 KB
#define LDS_B  (BN * BK)       // 8192 ushorts  = 16 KB
#define LDS_TILE (LDS_A + LDS_B)  // 24576 ushorts = 48 KB; 3 buffers = 144 KB

typedef __bf16 bf16x8 __attribute__((ext_vector_type(8)));
typedef float  f32x4  __attribute__((ext_vector_type(4)));
typedef float  f32x16 __attribute__((ext_vector_type(16)));

__device__ __forceinline__ unsigned short f2bf(float f) {
  return __builtin_bit_cast(unsigned short, (__bf16)f);
}
__device__ __forceinline__ float bf2f(unsigned short u) {
  return __builtin_bit_cast(float, (unsigned int)u << 16);
}
__device__ __forceinline__ ushort4 pack4(f32x4 f) {
  ushort4 o; o.x = f2bf(f.x); o.y = f2bf(f.y); o.z = f2bf(f.z); o.w = f2bf(f.w);
  return o;
}

__device__ __forceinline__ void async16(const void* g, void* l) {
  __builtin_amdgcn_global_load_lds(
      (const __attribute__((address_space(1))) unsigned int*)g,
      (__attribute__((address_space(3))) unsigned int*)l, 16, 0, 0);
}

// Input-side prep (runs FIRST): x,y,z -> Ib[8192][3072] bf16 (cols: x|y|z), P = bf16(x*y).
__global__ __launch_bounds__(256) void convert_kernel(
    const f32x4* __restrict__ x, const f32x4* __restrict__ y, const f32x4* __restrict__ z,
    ushort4* __restrict__ Ib4, ushort4* __restrict__ P4)
{
  int bid = blockIdx.x;
  int tid = threadIdx.x;
  int i = bid * 256 + tid;            // float4 index over [8192][256]
  f32x4 fx = x[i], fy = y[i], fz = z[i];
  size_t rb = (size_t)bid * 768;
  Ib4[rb + tid]       = pack4(fx);
  Ib4[rb + 256 + tid] = pack4(fy);
  Ib4[rb + 512 + tid] = pack4(fz);
  P4[i] = pack4(fx * fy);
}

// W-side prep (runs SECOND): Wsum[d][c] = bf16(sum_k W[d*16+k][c]); bsum = sum_k b.
// W is a 201 MB read-once stream -> NON-TEMPORAL loads (no-allocate): preserves
// the freshly-written Ib/P/Wsum in L3 for the GEMM.  [R13-verified: −8 µs]
__global__ __launch_bounds__(256) void wsum_kernel(
    const f32x4* __restrict__ W4, const float* __restrict__ b,
    ushort4* __restrict__ Wsum4, float* __restrict__ bsum)
{
  int bid = blockIdx.x;
  int tid = threadIdx.x;
  if (bid < 3072) {
    int g  = bid * 256 + tid;            // 0 .. 786431 float4 cols
    int d  = g / 768;
    int cq = g - d * 768;
    const f32x4* wrow = W4 + (size_t)d * (KD * K3 / 4);
    f32x4 s = __builtin_nontemporal_load(&wrow[cq]);
    #pragma unroll
    for (int k = 1; k < KD; ++k)
      s += __builtin_nontemporal_load(&wrow[(size_t)k * (K3 / 4) + cq]);
    Wsum4[g] = pack4(s);
  } else {
    int d = (bid - 3072) * 256 + tid;
    if (d < N_DIM) {
      float s = 0.f;
      #pragma unroll
      for (int k = 0; k < KD; ++k) s += b[d * KD + k];
      bsum[d] = s;
    }
  }
}

// GEMM C[m,n] = sum_k Ib[m,k]*Wsum[n,k]; out[m,n] = (C + bsum[n]) * P[m,n]
// R13 skeleton, MFMA upgraded 16x16x32 -> 32x32x16 (m119: 2495 vs ~2100 TF).
// Per wave 64x64 = 2x2 of 32x32 tiles; BK=64 = 4 kk-quarters of K=16.
// A/B lane map: row=lane&31, k=(lane>>5)*8 + [0..8). Fragment-software-pipelined
// halves (half = 2 kk = 8 ds_read + 8 MFMA), counted lgkmcnt(8), vmcnt(6).
__global__ __launch_bounds__(512, 2) void gemm_ep_kernel(
    const unsigned short* __restrict__ Ib, const unsigned short* __restrict__ Wsum,
    const float* __restrict__ bsum, const unsigned short* __restrict__ P,
    float* __restrict__ out)
{
  extern __shared__ unsigned short lds[];   // 3 * LDS_TILE ushorts = 144 KB

  // XCD-aware bijective swizzle: 256 blocks, 8 XCDs, 32 blocks each.
  int bid = blockIdx.x;
  int swz = (bid & 7) * 32 + (bid >> 3);
  int mt = swz >> 3;          // 0..31
  int nt = swz & 7;           // 0..7
  int m0 = mt * BM, n0 = nt * BN;

  int tid  = threadIdx.x;     // 0..511
  int lane = tid & 63;
  int wid  = tid >> 6;        // 0..7
  int wr = wid >> 1, wc = wid & 1;   // 4x2 wave grid, each wave 64x64 out
  int l31 = lane & 31;
  int l5  = lane >> 5;               // 0..1

  // staging geometry: A-tile 32KB = 4 rounds x (512 thr x 16B); B-tile 16KB = 2 rounds
  int row0 = tid >> 3;               // 0..63 (round adds 64)
  int ch0  = tid & 7;                // 16B chunk within 128B row
  int dofs = tid * 16;               // byte offset within an 8KB round
  int sc   = (ch0 ^ (row0 & 7)) << 3;    // pre-swizzled source chunk (ushort units)

  const unsigned short* Abase = Ib   + (size_t)m0 * K3;
  const unsigned short* Bbase = Wsum + (size_t)n0 * K3;

  f32x16 acc[2][2];
  #pragma unroll
  for (int i = 0; i < 2; ++i)
    #pragma unroll
    for (int j = 0; j < 2; ++j)
      acc[i][j] = (f32x16)(0.f);

  // stage full K-tile t (6 loads: 4 A rounds + 2 B rounds) into buffer slot.
  // LDS content: row r, chunk u holds global chunk u^(r&7) of row r (T2 both-sides).
  auto STAGE = [&](int slot, int t) {
    char* dst = (char*)(lds + slot * LDS_TILE);
    int k0 = t << 6;
    #pragma unroll
    for (int r = 0; r < 4; ++r)
      async16(Abase + (size_t)(row0 + r * 64) * K3 + k0 + sc, dst + dofs + r * 8192);
    char* dstB = dst + 2 * LDS_A;   // bytes
    #pragma unroll
    for (int r = 0; r < 2; ++r)
      async16(Bbase + (size_t)(row0 + r * 64) * K3 + k0 + sc, dstB + dofs + r * 8192);
  };

  // 8 ds_read_b128: fragments for kk-half h (kk = 2h, 2h+1) from a tile slot.
  // a[bi][q]: A rows wr*64+bi*32+l31, k-chunk (kk*2 + l5); b[bj][q] same on B.
  auto LOAD8 = [&](const unsigned short* pA, int h,
                   bf16x8 (&a)[2][2], bf16x8 (&b)[2][2]) {
    const unsigned short* pB = pA + LDS_A;
    #pragma unroll
    for (int bi = 0; bi < 2; ++bi) {
      int R = wr * 64 + bi * 32 + l31;
      #pragma unroll
      for (int q = 0; q < 2; ++q) {
        int c = ((h * 2 + q) << 1) + l5;          // logical chunk 0..7
        a[bi][q] = *(const bf16x8*)&pA[(R << 6) + ((c ^ (R & 7)) << 3)];
      }
    }
    #pragma unroll
    for (int bj = 0; bj < 2; ++bj) {
      int R = wc * 64 + bj * 32 + l31;
      #pragma unroll
      for (int q = 0; q < 2; ++q) {
        int c = ((h * 2 + q) << 1) + l5;
        b[bj][q] = *(const bf16x8*)&pB[(R << 6) + ((c ^ (R & 7)) << 3)];
      }
    }
  };
  // 8 MFMA (32x32x16): kk-half h = 2 kk-quarters x 2x2 blocks.
  auto MFMA8 = [&](bf16x8 (&a)[2][2], bf16x8 (&b)[2][2]) {
    __builtin_amdgcn_s_setprio(1);
    #pragma unroll
    for (int q = 0; q < 2; ++q)
      #pragma unroll
      for (int bi = 0; bi < 2; ++bi)
        #pragma unroll
        for (int bj = 0; bj < 2; ++bj)
          acc[bi][bj] = __builtin_amdgcn_mfma_f32_32x32x16_bf16(
              a[bi][q], b[bj][q], acc[bi][bj], 0, 0, 0);
    __builtin_amdgcn_s_setprio(0);
  };

  bf16x8 aA[2][2], bA[2][2], aB[2][2], bB[2][2];   // double-buffered fragment sets

  // One K-tile: enter with {aA,bA} = frags(t, half0) reads already issued.
  //   h0: read frags(t,h1)->B | stage t+2 | vmcnt(6) | lgkm(8) | MFMA(A) | bar
  //   h1: read frags(t+1,h0)->A |                     lgkm(8) | MFMA(B) | bar
  auto TILE = [&](int t, const unsigned short* pCur, const unsigned short* pNext,
                  int stSlot) {
    bool st = (t + 2) < NKT;
    // ---- half 0 ----
    LOAD8(pCur, 1, aB, bB);
    __builtin_amdgcn_sched_barrier(0);          // keep the 8-read group intact
    if (st) {
      STAGE(stSlot, t + 2);
      asm volatile("s_waitcnt vmcnt(6)" ::: "memory");   // tile t+1 landed
    } else {
      asm volatile("s_waitcnt vmcnt(0)" ::: "memory");
    }
    asm volatile("s_waitcnt lgkmcnt(8)" ::: "memory");   // frags(t,h0) ready
    __builtin_amdgcn_sched_barrier(0);                    // rule #18
    MFMA8(aA, bA);
    __builtin_amdgcn_s_barrier();
    // ---- half 1 ----
    LOAD8(pNext, 0, aA, bA);                    // frags(t+1,h0); safe after bar
    __builtin_amdgcn_sched_barrier(0);
    asm volatile("s_waitcnt lgkmcnt(8)" ::: "memory");   // frags(t,h1) ready
    __builtin_amdgcn_sched_barrier(0);
    MFMA8(aB, bB);
    __builtin_amdgcn_s_barrier();
  };

  const unsigned short* s0 = lds;
  const unsigned short* s1 = lds + LDS_TILE;
  const unsigned short* s2 = lds + 2 * LDS_TILE;

  // prologue: stage tiles 0,1; then issue frags(0, half0)
  STAGE(0, 0);
  STAGE(1, 1);
  asm volatile("s_waitcnt vmcnt(6)" ::: "memory");   // tile 0 landed; tile 1 in flight
  __builtin_amdgcn_s_barrier();
  LOAD8(s0, 0, aA, bA);
  __builtin_amdgcn_sched_barrier(0);

  #pragma unroll 1
  for (int t = 0; t < NKT; t += 3) {
    TILE(t,     s0, s1, 2);
    TILE(t + 1, s1, s2, 0);
    TILE(t + 2, s2, s0, 1);
  }

  // Epilogue: 32x32 C/D layout col = lane&31, row = (reg&3)+8*(reg>>2)+4*(lane>>5)
  // [verified m74/m101].  Lanes 0..31 span 32 consecutive n -> 128B coalesced.
  #pragma unroll
  for (int bi = 0; bi < 2; ++bi) {
    #pragma unroll
    for (int bj = 0; bj < 2; ++bj) {
      int n = n0 + wc * 64 + bj * 32 + l31;
      float bs = bsum[n];
      #pragma unroll
      for (int r = 0; r < 16; ++r) {
        int m = m0 + wr * 64 + bi * 32 + (r & 3) + 8 * (r >> 2) + 4 * l5;
        size_t idx = (size_t)m * N_DIM + n;
        out[idx] = (acc[bi][bj][r] + bs) * bf2f(P[idx]);
      }
    }
  }
}

extern "C" void kernel_launch(void* const* d_in, const int* in_sizes, int n_in,
                              void* d_out, int out_size, void* d_ws, size_t ws_size,
                              hipStream_t stream) {
  const float* x = (const float*)d_in[0];
  const float* y = (const float*)d_in[1];
  const float* z = (const float*)d_in[2];
  const float* W = (const float*)d_in[3];
  const float* b = (const float*)d_in[4];
  float* out = (float*)d_out;

  // ws layout: Ib bf16 [8192*3072]; Wsum bf16 [1024*3072]; P bf16 [8192*1024]; bsum f32[1024]
  unsigned short* Ib   = (unsigned short*)d_ws;
  unsigned short* Wsum = Ib + (size_t)M_ROWS * K3;
  unsigned short* P    = Wsum + (size_t)N_DIM * K3;
  float*          bsum = (float*)(P + (size_t)M_ROWS * N_DIM);

  // 1) input conversion FIRST: Ib/P land in L3 and stay there (W won't evict them)
  convert_kernel<<<8192, 256, 0, stream>>>(
      (const f32x4*)x, (const f32x4*)y, (const f32x4*)z,
      (ushort4*)Ib, (ushort4*)P);

  // 2) W-side prep with NON-TEMPORAL W reads (no-allocate: preserves L3 for GEMM)
  wsum_kernel<<<3076, 256, 0, stream>>>((const f32x4*)W, b, (ushort4*)Wsum, bsum);

  // 3) GEMM + epilogue: 32 x 8 tiles of 256x128, 144 KB dynamic LDS
  gemm_ep_kernel<<<256, 512, 3 * LDS_TILE * sizeof(unsigned short), stream>>>(
      Ib, Wsum, bsum, P, out);
}

// Round 15
// 113.498 us; speedup vs baseline: 1.0393x; 1.0393x over previous
//
#include <hip/hip_runtime.h>

// Problem constants
#define M_ROWS 8192            // B*L = 4*2048
#define N_DIM  1024            // D
#define K3     3072            // 3*D
#define KD     16              // K_DIM
#define NKT    48              // K3 / BK (multiple of 3)
#define BM     256
#define BN     128
#define BK     64
#define LDS_A  (BM * BK)       // 16384 ushorts = 32 KB
#define LDS_B  (BN * BK)       // 8192 ushorts  = 16 KB
#define LDS_TILE (LDS_A + LDS_B)  // 24576 ushorts = 48 KB; 3 buffers = 144 KB

typedef __bf16 bf16x8 __attribute__((ext_vector_type(8)));
typedef float  f32x4  __attribute__((ext_vector_type(4)));

__device__ __forceinline__ unsigned short f2bf(float f) {
  return __builtin_bit_cast(unsigned short, (__bf16)f);
}
__device__ __forceinline__ float bf2f(unsigned short u) {
  return __builtin_bit_cast(float, (unsigned int)u << 16);
}
__device__ __forceinline__ ushort4 pack4(f32x4 f) {
  ushort4 o; o.x = f2bf(f.x); o.y = f2bf(f.y); o.z = f2bf(f.z); o.w = f2bf(f.w);
  return o;
}

__device__ __forceinline__ void async16(const void* g, void* l) {
  __builtin_amdgcn_global_load_lds(
      (const __attribute__((address_space(1))) unsigned int*)g,
      (__attribute__((address_space(3))) unsigned int*)l, 16, 0, 0);
}

// Input-side prep (runs FIRST): x,y,z -> Ib[8192][3072] bf16 (cols: x|y|z), P = bf16(x*y).
// Plain cached loads/stores — Ib/P land and stay in L3 for the GEMM.
__global__ __launch_bounds__(256) void convert_kernel(
    const f32x4* __restrict__ x, const f32x4* __restrict__ y, const f32x4* __restrict__ z,
    ushort4* __restrict__ Ib4, ushort4* __restrict__ P4)
{
  int bid = blockIdx.x;
  int tid = threadIdx.x;
  int i = bid * 256 + tid;            // float4 index over [8192][256]
  f32x4 fx = x[i], fy = y[i], fz = z[i];
  size_t rb = (size_t)bid * 768;
  Ib4[rb + tid]       = pack4(fx);
  Ib4[rb + 256 + tid] = pack4(fy);
  Ib4[rb + 512 + tid] = pack4(fz);
  P4[i] = pack4(fx * fy);
}

// W-side prep (runs SECOND): Wsum[d][c] = bf16(sum_k W[d*16+k][c]); bsum = sum_k b.
// W is a 201 MB read-once stream -> NON-TEMPORAL loads (no-allocate): it must not
// evict the freshly-written Ib/P/Wsum from L3 before the GEMM reads them.
// [R13-verified mechanism: −8 µs]
__global__ __launch_bounds__(256) void wsum_kernel(
    const f32x4* __restrict__ W4, const float* __restrict__ b,
    ushort4* __restrict__ Wsum4, float* __restrict__ bsum)
{
  int bid = blockIdx.x;
  int tid = threadIdx.x;
  if (bid < 3072) {
    int g  = bid * 256 + tid;            // 0 .. 786431 float4 cols
    int d  = g / 768;
    int cq = g - d * 768;
    const f32x4* wrow = W4 + (size_t)d * (KD * K3 / 4);
    f32x4 s = __builtin_nontemporal_load(&wrow[cq]);
    #pragma unroll
    for (int k = 1; k < KD; ++k)
      s += __builtin_nontemporal_load(&wrow[(size_t)k * (K3 / 4) + cq]);
    Wsum4[g] = pack4(s);
  } else {
    int d = (bid - 3072) * 256 + tid;
    if (d < N_DIM) {
      float s = 0.f;
      #pragma unroll
      for (int k = 0; k < KD; ++k) s += b[d * KD + k];
      bsum[d] = s;
    }
  }
}

// GEMM C[m,n] = sum_k Ib[m,k]*Wsum[n,k]; out[m,n] = (C + bsum[n]) * P[m,n]
// [R13 verbatim — best measured 113.6 µs, ~930 TF] BM=256 x BN=128, BK=64,
// 8 waves (4Mx2N, 64x64 each), 3-deep LDS pipeline, fragment-software-pipelined
// with counted lgkmcnt(8), counted vmcnt(6), 2 barriers/K-tile, T2 chunk swizzle,
// XCD swizzle, setprio.  16x16x32 MFMA (R14 measured: 32x32x16 is 4 µs WORSE —
// only 4 independent accs, 2-deep dependent MFMA chains starve the pipe).
__global__ __launch_bounds__(512, 2) void gemm_ep_kernel(
    const unsigned short* __restrict__ Ib, const unsigned short* __restrict__ Wsum,
    const float* __restrict__ bsum, const unsigned short* __restrict__ P,
    float* __restrict__ out)
{
  extern __shared__ unsigned short lds[];   // 3 * LDS_TILE ushorts = 144 KB

  // XCD-aware bijective swizzle: 256 blocks, 8 XCDs, 32 blocks each.
  int bid = blockIdx.x;
  int swz = (bid & 7) * 32 + (bid >> 3);
  int mt = swz >> 3;          // 0..31
  int nt = swz & 7;           // 0..7
  int m0 = mt * BM, n0 = nt * BN;

  int tid  = threadIdx.x;     // 0..511
  int lane = tid & 63;
  int wid  = tid >> 6;        // 0..7
  int wr = wid >> 1, wc = wid & 1;   // 4x2 wave grid, each wave 64x64 out
  int fr = lane & 15;
  int hi = lane >> 4;                // 0..3

  // staging geometry: A-tile 32KB = 4 rounds x (512 thr x 16B); B-tile 16KB = 2 rounds
  int row0 = tid >> 3;               // 0..63 (round adds 64)
  int ch0  = tid & 7;                // 16B chunk within 128B row
  int dofs = tid * 16;               // byte offset within an 8KB round
  int sc   = (ch0 ^ (row0 & 7)) << 3;    // pre-swizzled source chunk (ushort units)

  const unsigned short* Abase = Ib   + (size_t)m0 * K3;
  const unsigned short* Bbase = Wsum + (size_t)n0 * K3;

  f32x4 acc[4][4];
  #pragma unroll
  for (int i = 0; i < 4; ++i)
    #pragma unroll
    for (int j = 0; j < 4; ++j)
      acc[i][j] = f32x4{0.f, 0.f, 0.f, 0.f};

  // stage full K-tile t (6 loads: 4 A rounds + 2 B rounds) into buffer slot.
  // LDS content: row r, chunk u holds global chunk u^(r&7) of row r (T2 both-sides).
  auto STAGE = [&](int slot, int t) {
    char* dst = (char*)(lds + slot * LDS_TILE);
    int k0 = t << 6;
    #pragma unroll
    for (int r = 0; r < 4; ++r)
      async16(Abase + (size_t)(row0 + r * 64) * K3 + k0 + sc, dst + dofs + r * 8192);
    char* dstB = dst + 2 * LDS_A;   // bytes
    #pragma unroll
    for (int r = 0; r < 2; ++r)
      async16(Bbase + (size_t)(row0 + r * 64) * K3 + k0 + sc, dstB + dofs + r * 8192);
  };

  // 8 ds_read_b128: fragments for sub-k kk from a tile slot
  auto LOAD8 = [&](const unsigned short* pA, int kk, bf16x8 (&a)[4], bf16x8 (&b)[4]) {
    const unsigned short* pB = pA + LDS_A;
    int c = (kk << 2) + hi;                 // logical chunk 0..7
    #pragma unroll
    for (int i = 0; i < 4; ++i) {
      int R = wr * 64 + i * 16 + fr;
      a[i] = *(const bf16x8*)&pA[(R << 6) + ((c ^ (R & 7)) << 3)];
    }
    #pragma unroll
    for (int j = 0; j < 4; ++j) {
      int R = wc * 64 + j * 16 + fr;
      b[j] = *(const bf16x8*)&pB[(R << 6) + ((c ^ (R & 7)) << 3)];
    }
  };
  auto MFMA16 = [&](bf16x8 (&a)[4], bf16x8 (&b)[4]) {
    __builtin_amdgcn_s_setprio(1);
    #pragma unroll
    for (int i = 0; i < 4; ++i)
      #pragma unroll
      for (int j = 0; j < 4; ++j)
        acc[i][j] = __builtin_amdgcn_mfma_f32_16x16x32_bf16(a[i], b[j], acc[i][j], 0, 0, 0);
    __builtin_amdgcn_s_setprio(0);
  };

  bf16x8 aA[4], bA[4], aB[4], bB[4];   // double-buffered fragment sets

  // One K-tile: enter with {aA,bA} = frags(t,kk0) reads already issued.
  //   kk0: read frags(t,kk1)->B | stage t+2 | vmcnt(6) | lgkm(8) | MFMA(A) | bar
  //   kk1: read frags(t+1,kk0)->A |                     lgkm(8) | MFMA(B) | bar
  auto TILE = [&](int t, const unsigned short* pCur, const unsigned short* pNext,
                  int stSlot) {
    bool st = (t + 2) < NKT;
    // ---- phase kk0 ----
    LOAD8(pCur, 1, aB, bB);
    __builtin_amdgcn_sched_barrier(0);          // keep the 8-read group intact
    if (st) {
      STAGE(stSlot, t + 2);
      asm volatile("s_waitcnt vmcnt(6)" ::: "memory");   // tile t+1 landed
    } else {
      asm volatile("s_waitcnt vmcnt(0)" ::: "memory");
    }
    asm volatile("s_waitcnt lgkmcnt(8)" ::: "memory");   // frags(t,kk0) ready
    __builtin_amdgcn_sched_barrier(0);                    // rule #18
    MFMA16(aA, bA);
    __builtin_amdgcn_s_barrier();
    // ---- phase kk1 ----
    LOAD8(pNext, 0, aA, bA);                    // frags(t+1,kk0); safe after bar
    __builtin_amdgcn_sched_barrier(0);
    asm volatile("s_waitcnt lgkmcnt(8)" ::: "memory");   // frags(t,kk1) ready
    __builtin_amdgcn_sched_barrier(0);
    MFMA16(aB, bB);
    __builtin_amdgcn_s_barrier();
  };

  const unsigned short* s0 = lds;
  const unsigned short* s1 = lds + LDS_TILE;
  const unsigned short* s2 = lds + 2 * LDS_TILE;

  // prologue: stage tiles 0,1; then issue frags(0,kk0)
  STAGE(0, 0);
  STAGE(1, 1);
  asm volatile("s_waitcnt vmcnt(6)" ::: "memory");   // tile 0 landed; tile 1 in flight
  __builtin_amdgcn_s_barrier();
  LOAD8(s0, 0, aA, bA);
  __builtin_amdgcn_sched_barrier(0);

  #pragma unroll 1
  for (int t = 0; t < NKT; t += 3) {
    TILE(t,     s0, s1, 2);
    TILE(t + 1, s1, s2, 0);
    TILE(t + 2, s2, s0, 1);
  }

  // Epilogue: C/D layout col = lane&15, row = (lane>>4)*4 + reg  [verified m89/m91]
  #pragma unroll
  for (int i = 0; i < 4; ++i) {
    #pragma unroll
    for (int j = 0; j < 4; ++j) {
      int n = n0 + wc * 64 + j * 16 + fr;
      float bs = bsum[n];
      #pragma unroll
      for (int r = 0; r < 4; ++r) {
        int m = m0 + wr * 64 + i * 16 + hi * 4 + r;
        size_t idx = (size_t)m * N_DIM + n;
        out[idx] = (acc[i][j][r] + bs) * bf2f(P[idx]);
      }
    }
  }
}

extern "C" void kernel_launch(void* const* d_in, const int* in_sizes, int n_in,
                              void* d_out, int out_size, void* d_ws, size_t ws_size,
                              hipStream_t stream) {
  const float* x = (const float*)d_in[0];
  const float* y = (const float*)d_in[1];
  const float* z = (const float*)d_in[2];
  const float* W = (const float*)d_in[3];
  const float* b = (const float*)d_in[4];
  float* out = (float*)d_out;

  // ws layout: Ib bf16 [8192*3072]; Wsum bf16 [1024*3072]; P bf16 [8192*1024]; bsum f32[1024]
  unsigned short* Ib   = (unsigned short*)d_ws;
  unsigned short* Wsum = Ib + (size_t)M_ROWS * K3;
  unsigned short* P    = Wsum + (size_t)N_DIM * K3;
  float*          bsum = (float*)(P + (size_t)M_ROWS * N_DIM);

  // 1) input conversion FIRST: Ib/P land in L3 and stay there (W won't evict them)
  convert_kernel<<<8192, 256, 0, stream>>>(
      (const f32x4*)x, (const f32x4*)y, (const f32x4*)z,
      (ushort4*)Ib, (ushort4*)P);

  // 2) W-side prep with NON-TEMPORAL W reads (no-allocate: preserves L3 for GEMM)
  wsum_kernel<<<3076, 256, 0, stream>>>((const f32x4*)W, b, (ushort4*)Wsum, bsum);

  // 3) GEMM + epilogue: 32 x 8 tiles of 256x128, 144 KB dynamic LDS
  gemm_ep_kernel<<<256, 512, 3 * LDS_TILE * sizeof(unsigned short), stream>>>(
      Ib, Wsum, bsum, P, out);
}